// Round 5
// baseline (89.125 us; speedup 1.0000x reference)
//
#include <hip/hip_runtime.h>
#include <math.h>

#define B 32
#define N 1024
#define W 128
#define R 4
#define EPSC 1e-8f

typedef float f32x4 __attribute__((ext_vector_type(4)));

// ---- ws layout (in floats) ----
#define WS_SUM   0                              // 1 float
#define WS_KSUM  64                             // B*5 softmax denominators
#define WS_BW    256                            // B*32*R*N
#define WS_FW    (WS_BW + B*32*R*N)             // B*R*N
#define WS_ER    (WS_FW + B*R*N)                // B*R*N  exp(cos) read keys
#define WS_EW    (WS_ER + B*R*N)                // B*N    exp(cos*wstr) write key
#define WS_WW    (WS_EW + B*N)                  // B*N

// ---- out offsets (in floats) ----
#define O_RR    0
#define O_MEM   (O_RR + B*R*W)
#define O_LINK  (O_MEM + B*N*W)
#define O_USAGE (O_LINK + B*N*N)
#define O_PREC  (O_USAGE + B*N)
#define O_NRW   (O_PREC + B*N)

// ===================== K1: cosine scores + exp + partial sums =====================
// grid B*64 (16 rows/block), block 256. 16 lanes per row -> 4-level reduce.
// No-max softmax: cos in [-1,1], write score in [-2,2] -> exp safe directly.
__global__ void k1_scores(const float* __restrict__ mem,
                          const float* __restrict__ rkeys,
                          const float* __restrict__ wkey,
                          const float* __restrict__ wstr,
                          float* __restrict__ ws) {
    int bx = blockIdx.x;
    int b = bx >> 6;
    int n0 = (bx & 63) << 4;
    int t = threadIdx.x;
    __shared__ float keys[5][W];
    __shared__ float knorm[5];
    __shared__ float epart[5][16];
    for (int idx = t; idx < 5 * W; idx += 256) {
        int r = idx >> 7, w = idx & 127;
        keys[r][w] = (r < 4) ? rkeys[(b * R + r) * W + w] : wkey[b * W + w];
    }
    __syncthreads();
    if (t < 160) {
        int kidx = t >> 5, l = t & 31;
        float s = 0.f;
        #pragma unroll
        for (int c = 0; c < 4; ++c) { float v = keys[kidx][l * 4 + c]; s += v * v; }
        #pragma unroll
        for (int st = 1; st <= 16; st <<= 1) s += __shfl_xor(s, st);
        if (l == 0) knorm[kidx] = sqrtf(s);
    }
    __syncthreads();
    int l16 = t & 15;
    int rloc = t >> 4;          // 0..15
    int n = n0 + rloc;
    const float* mrow = mem + ((size_t)(b * N + n)) * W + l16 * 8;
    float4 a  = *reinterpret_cast<const float4*>(mrow);
    float4 a2 = *reinterpret_cast<const float4*>(mrow + 4);
    float mm = a.x*a.x + a.y*a.y + a.z*a.z + a.w*a.w
             + a2.x*a2.x + a2.y*a2.y + a2.z*a2.z + a2.w*a2.w;
    float d[5];
    #pragma unroll
    for (int r = 0; r < 5; ++r) {
        float4 k1v = *reinterpret_cast<const float4*>(&keys[r][l16 * 8]);
        float4 k2v = *reinterpret_cast<const float4*>(&keys[r][l16 * 8 + 4]);
        d[r] = a.x*k1v.x + a.y*k1v.y + a.z*k1v.z + a.w*k1v.w
             + a2.x*k2v.x + a2.y*k2v.y + a2.z*k2v.z + a2.w*k2v.w;
    }
    #pragma unroll
    for (int st = 1; st <= 8; st <<= 1) {
        mm += __shfl_xor(mm, st);
        #pragma unroll
        for (int r = 0; r < 5; ++r) d[r] += __shfl_xor(d[r], st);
    }
    if (l16 == 0) {
        float mn = sqrtf(mm);
        float e[5];
        #pragma unroll
        for (int r = 0; r < 4; ++r) {
            float c = d[r] / fmaxf(knorm[r] * mn, EPSC);
            e[r] = expf(c);
            ws[WS_ER + (b * R + r) * N + n] = e[r];
        }
        float cw = d[4] / fmaxf(knorm[4] * mn, EPSC);
        e[4] = expf(cw * wstr[b]);
        ws[WS_EW + b * N + n] = e[4];
        #pragma unroll
        for (int q = 0; q < 5; ++q) epart[q][rloc] = e[q];
    }
    __syncthreads();
    if (t < 80) {
        int q = t >> 4, i = t & 15;
        float v = epart[q][i];
        #pragma unroll
        for (int st = 1; st <= 8; st <<= 1) v += __shfl_xor(v, st);
        if (i == 0) atomicAdd(&ws[WS_KSUM + b * 5 + q], v);
    }
}

// ===================== K2: allocation cumprod + ww (lightweight now) =====================
// grid B, block 1024 (one element per thread).
__global__ void k2_soft(const float* __restrict__ usage,
                        const float* __restrict__ agate,
                        const float* __restrict__ wgate,
                        float* __restrict__ ws) {
    int b = blockIdx.x, t = threadIdx.x;
    int lane = t & 63, wv = t >> 6;       // 16 waves
    __shared__ float wsc[16];
    __shared__ float red[16];

    float sw = ws[WS_KSUM + b * 5 + 4];
    float wcv = ws[WS_EW + b * N + t] / sw;

    // ---- exclusive cumprod scan of usage ----
    float u = usage[b * N + t];
    float incl = u;
    #pragma unroll
    for (int s = 1; s <= 32; s <<= 1) {
        float up = __shfl_up(incl, s);
        if (lane >= s) incl *= up;
    }
    if (lane == 63) wsc[wv] = incl;
    __syncthreads();
    if (t < 16) {
        float v = wsc[t];
        #pragma unroll
        for (int s = 1; s <= 8; s <<= 1) {
            float up = __shfl_up(v, s);
            if (lane >= s) v *= up;
        }
        wsc[t] = v;  // inclusive over waves
    }
    __syncthreads();
    float woff = (wv == 0) ? 1.f : wsc[wv - 1];
    float eu = __shfl_up(incl, 1);
    float excl = (lane == 0 ? 1.f : eu) * woff;
    float alloc = (1.f - u) * excl;

    float wwv = (agate[b] * (alloc - wcv) + wcv) * wgate[b];
    ws[WS_WW + b * N + t] = wwv;

    float s6 = wwv;
    #pragma unroll
    for (int s = 1; s <= 32; s <<= 1) s6 += __shfl_xor(s6, s);
    __syncthreads();
    if (lane == 0) red[wv] = s6;
    __syncthreads();
    if (t == 0) {
        float acc = 0.f;
        for (int w2 = 0; w2 < 16; ++w2) acc += red[w2];
        atomicAdd(&ws[WS_SUM], acc);
    }
}

// ===================== K3: single pass over L (v4) =====================
// grid B*32 (32-row strips), block 256, 4 blocks/CU. Thread owns 4 fixed cols.
// 8-row batched loads (MLP=8), bw register-accumulated, fw via LDS
// transpose-reduce, NT stores for link_new.
__global__ void k3_link(const float* __restrict__ L,
                        const float* __restrict__ rw,
                        const float* __restrict__ prec,
                        float* __restrict__ ws,
                        float* __restrict__ out) {
    int bx = blockIdx.x;
    int b = bx >> 5;
    int strip = bx & 31;
    int i0 = strip << 5;
    int t = threadIdx.x;
    __shared__ float scratch[256][36];   // padded: float4-aligned, low-conflict
    __shared__ float ww_row[32];
    __shared__ float rw_row[R][32];

    if (t < 32) ww_row[t] = ws[WS_WW + b * N + i0 + t];
    if (t >= 64 && t < 192) {
        int idx = t - 64;
        int r = idx >> 5, i = idx & 31;
        rw_row[r][i] = rw[(b * R + r) * N + i0 + i];
    }
    __syncthreads();

    int j0 = 4 * t;
    float4 wwj = *reinterpret_cast<const float4*>(ws + WS_WW + b * N + j0);
    float4 pj  = *reinterpret_cast<const float4*>(prec + b * N + j0);
    float4 rwj[R];
    #pragma unroll
    for (int r = 0; r < R; ++r)
        rwj[r] = *reinterpret_cast<const float4*>(rw + (b * R + r) * N + j0);
    float4 bwa[R];
    #pragma unroll
    for (int r = 0; r < R; ++r) bwa[r] = make_float4(0.f, 0.f, 0.f, 0.f);

    const float* Lr = L + ((size_t)(b * N + i0)) * N + j0;
    float* Or = out + O_LINK + ((size_t)(b * N + i0)) * N + j0;

    int g = t >> 3, kk = t & 7;   // reduce-phase role: output g, reducer kk

    for (int batch = 0; batch < 4; ++batch) {
        // --- issue 8 independent loads ---
        float4 v[8];
        #pragma unroll
        for (int k = 0; k < 8; ++k)
            v[k] = *reinterpret_cast<const float4*>(Lr + (size_t)(batch * 8 + k) * N);

        float4 fwp[8];
        #pragma unroll
        for (int k = 0; k < 8; ++k) {
            int row = batch * 8 + k;
            float wi = ww_row[row];
            float c = 1.f - wi;
            f32x4 o;
            o.x = (c - wwj.x) * v[k].x + wi * pj.x;
            o.y = (c - wwj.y) * v[k].y + wi * pj.y;
            o.z = (c - wwj.z) * v[k].z + wi * pj.z;
            o.w = (c - wwj.w) * v[k].w + wi * pj.w;
            __builtin_nontemporal_store(o,
                reinterpret_cast<f32x4*>(Or + (size_t)row * N));
            float4 f;
            f.x = v[k].x*rwj[0].x + v[k].y*rwj[0].y + v[k].z*rwj[0].z + v[k].w*rwj[0].w;
            f.y = v[k].x*rwj[1].x + v[k].y*rwj[1].y + v[k].z*rwj[1].z + v[k].w*rwj[1].w;
            f.z = v[k].x*rwj[2].x + v[k].y*rwj[2].y + v[k].z*rwj[2].z + v[k].w*rwj[2].w;
            f.w = v[k].x*rwj[3].x + v[k].y*rwj[3].y + v[k].z*rwj[3].z + v[k].w*rwj[3].w;
            fwp[k] = f;
            #pragma unroll
            for (int r = 0; r < R; ++r) {
                float q = rw_row[r][row];
                bwa[r].x += q * v[k].x; bwa[r].y += q * v[k].y;
                bwa[r].z += q * v[k].z; bwa[r].w += q * v[k].w;
            }
        }

        // --- fw transpose-reduce: scratch[t][row_k*4 + r] = partial ---
        #pragma unroll
        for (int k = 0; k < 8; ++k)
            *reinterpret_cast<float4*>(&scratch[t][k * 4]) = fwp[k];
        __syncthreads();
        float s = 0.f;
        #pragma unroll
        for (int m = 0; m < 32; ++m) s += scratch[kk + 8 * m][g];
        s += __shfl_xor(s, 1);
        s += __shfl_xor(s, 2);
        s += __shfl_xor(s, 4);
        if (kk == 0) {
            int rowk = g >> 2, r = g & 3;
            ws[WS_FW + (b * R + r) * N + i0 + batch * 8 + rowk] = s;
        }
        __syncthreads();
    }

    // bw: per-strip partials to ws (no global atomics)
    float* bwout = ws + WS_BW + (size_t)(b * 32 + strip) * R * N;
    #pragma unroll
    for (int r = 0; r < R; ++r)
        *reinterpret_cast<float4*>(bwout + r * N + j0) = bwa[r];
}

// ===================== K4: finalize =====================
// grid B*16 (64-row chunks), block 256.
__global__ void k4_final(const float* __restrict__ mem,
                         const float* __restrict__ usage,
                         const float* __restrict__ prec,
                         const float* __restrict__ rmodes,
                         const float* __restrict__ rstr,
                         const float* __restrict__ fgates,
                         const float* __restrict__ ev,
                         const float* __restrict__ wvec,
                         float* __restrict__ ws,
                         float* __restrict__ out) {
    int bx = blockIdx.x;
    int b = bx >> 4;
    int n0 = (bx & 15) << 6;
    int t = threadIdx.x;
    __shared__ float nrw[R][64];
    __shared__ float wwl[64];
    __shared__ float rrl[2][R][W];

    // phase 1: new_rw (256 = R*64 work items); content weight finished inline
    {
        int r = t >> 6, nl = t & 63, n = n0 + nl;
        float bs = 0.f;
        #pragma unroll
        for (int tile = 0; tile < 32; ++tile)
            bs += ws[WS_BW + ((size_t)(b * 32 + tile) * R + r) * N + n];
        float fwv = ws[WS_FW + (b * R + r) * N + n];
        float cv  = ws[WS_ER + (b * R + r) * N + n] / ws[WS_KSUM + b * 5 + r]
                    * rstr[b * R + r];
        float m0 = rmodes[(b * R + r) * 3 + 0];
        float m1 = rmodes[(b * R + r) * 3 + 1];
        float m2 = rmodes[(b * R + r) * 3 + 2];
        float v = fwv * m0 + bs * m1 + cv * m2;
        out[O_NRW + (b * R + r) * N + n] = v;
        nrw[r][nl] = v;
    }
    __syncthreads();

    // phase 2: usage_new, precedence_new
    if (t < 64) {
        int n = n0 + t;
        float ret = 1.f;
        #pragma unroll
        for (int r = 0; r < R; ++r) ret *= (1.f - fgates[b * R + r] * nrw[r][t]);
        float u = usage[b * N + n];
        float w = ws[WS_WW + b * N + n];
        out[O_USAGE + b * N + n] = (u + w - u * w) * ret;
        float S = ws[WS_SUM];
        out[O_PREC + b * N + n] = (1.f - S) * prec[b * N + n] + w;
        wwl[t] = w;
    }
    __syncthreads();

    // phase 3: memory_new + read_result partial
    int wi = t & 127, half = t >> 7;
    float er = ev[b * W + wi], wvv = wvec[b * W + wi];
    float acc[R] = {0.f, 0.f, 0.f, 0.f};
    for (int k = 0; k < 32; ++k) {
        int nl = half * 32 + k;
        int n = n0 + nl;
        size_t off = ((size_t)(b * N + n)) * W + wi;
        float m = mem[off];
        float wn = wwl[nl];
        out[O_MEM + off] = m * (1.f - wn * er) + wn * wvv;
        #pragma unroll
        for (int r = 0; r < R; ++r) acc[r] += nrw[r][nl] * m;
    }
    #pragma unroll
    for (int r = 0; r < R; ++r) rrl[half][r][wi] = acc[r];
    __syncthreads();
    for (int idx = t; idx < R * W; idx += 256) {
        int r = idx >> 7, w2 = idx & 127;
        atomicAdd(&out[O_RR + (b * R + r) * W + w2], rrl[0][r][w2] + rrl[1][r][w2]);
    }
}

extern "C" void kernel_launch(void* const* d_in, const int* in_sizes, int n_in,
                              void* d_out, int out_size, void* d_ws, size_t ws_size,
                              hipStream_t stream) {
    const float* mem    = (const float*)d_in[0];
    const float* L      = (const float*)d_in[1];
    const float* usage  = (const float*)d_in[2];
    const float* prec   = (const float*)d_in[3];
    const float* rw     = (const float*)d_in[4];
    const float* rkeys  = (const float*)d_in[5];
    const float* rstr   = (const float*)d_in[6];
    const float* rmodes = (const float*)d_in[7];
    const float* wkey   = (const float*)d_in[8];
    const float* wstr   = (const float*)d_in[9];
    const float* ag     = (const float*)d_in[10];
    const float* wg     = (const float*)d_in[11];
    const float* wv     = (const float*)d_in[12];
    const float* ev     = (const float*)d_in[13];
    const float* fg     = (const float*)d_in[14];
    float* out = (float*)d_out;
    float* ws  = (float*)d_ws;

    (void)hipMemsetAsync(ws, 0, 1024, stream);                               // sum_ww + ksum
    (void)hipMemsetAsync(out, 0, (size_t)B * R * W * sizeof(float), stream); // read_result

    k1_scores<<<B * 64, 256, 0, stream>>>(mem, rkeys, wkey, wstr, ws);
    k2_soft<<<B, 1024, 0, stream>>>(usage, ag, wg, ws);
    k3_link<<<B * 32, 256, 0, stream>>>(L, rw, prec, ws, out);
    k4_final<<<B * 16, 256, 0, stream>>>(mem, usage, prec, rmodes, rstr, fg, ev, wv, ws, out);
}

// Round 6
// 84.573 us; speedup vs baseline: 1.0538x; 1.0538x over previous
//
#include <hip/hip_runtime.h>
#include <math.h>

#define B 32
#define N 1024
#define W 128
#define R 4
#define EPSC 1e-8f

typedef float f32x4 __attribute__((ext_vector_type(4)));

// ---- ws layout (in floats) ----
#define WS_SUM   0                              // 1 float
#define WS_KSUM  64                             // B*5 softmax denominators
#define WS_BW    256                            // B*16*R*N
#define WS_FW    (WS_BW + B*16*R*N)             // B*R*N
#define WS_ER    (WS_FW + B*R*N)                // B*R*N  exp(cos) read keys
#define WS_EW    (WS_ER + B*R*N)                // B*N    exp(cos*wstr) write key
#define WS_WW    (WS_EW + B*N)                  // B*N

// ---- out offsets (in floats) ----
#define O_RR    0
#define O_MEM   (O_RR + B*R*W)
#define O_LINK  (O_MEM + B*N*W)
#define O_USAGE (O_LINK + B*N*N)
#define O_PREC  (O_USAGE + B*N)
#define O_NRW   (O_PREC + B*N)

// ===================== K1: cosine scores + exp + partial sums =====================
// grid B*64 (16 rows/block), block 256. 16 lanes per row -> 4-level reduce.
// No-max softmax: cos in [-1,1], write score in [-2,2] -> exp safe directly.
__global__ void k1_scores(const float* __restrict__ mem,
                          const float* __restrict__ rkeys,
                          const float* __restrict__ wkey,
                          const float* __restrict__ wstr,
                          float* __restrict__ ws) {
    int bx = blockIdx.x;
    int b = bx >> 6;
    int n0 = (bx & 63) << 4;
    int t = threadIdx.x;
    __shared__ float keys[5][W];
    __shared__ float knorm[5];
    __shared__ float epart[5][16];
    for (int idx = t; idx < 5 * W; idx += 256) {
        int r = idx >> 7, w = idx & 127;
        keys[r][w] = (r < 4) ? rkeys[(b * R + r) * W + w] : wkey[b * W + w];
    }
    __syncthreads();
    if (t < 160) {
        int kidx = t >> 5, l = t & 31;
        float s = 0.f;
        #pragma unroll
        for (int c = 0; c < 4; ++c) { float v = keys[kidx][l * 4 + c]; s += v * v; }
        #pragma unroll
        for (int st = 1; st <= 16; st <<= 1) s += __shfl_xor(s, st);
        if (l == 0) knorm[kidx] = sqrtf(s);
    }
    __syncthreads();
    int l16 = t & 15;
    int rloc = t >> 4;          // 0..15
    int n = n0 + rloc;
    const float* mrow = mem + ((size_t)(b * N + n)) * W + l16 * 8;
    float4 a  = *reinterpret_cast<const float4*>(mrow);
    float4 a2 = *reinterpret_cast<const float4*>(mrow + 4);
    float mm = a.x*a.x + a.y*a.y + a.z*a.z + a.w*a.w
             + a2.x*a2.x + a2.y*a2.y + a2.z*a2.z + a2.w*a2.w;
    float d[5];
    #pragma unroll
    for (int r = 0; r < 5; ++r) {
        float4 k1v = *reinterpret_cast<const float4*>(&keys[r][l16 * 8]);
        float4 k2v = *reinterpret_cast<const float4*>(&keys[r][l16 * 8 + 4]);
        d[r] = a.x*k1v.x + a.y*k1v.y + a.z*k1v.z + a.w*k1v.w
             + a2.x*k2v.x + a2.y*k2v.y + a2.z*k2v.z + a2.w*k2v.w;
    }
    #pragma unroll
    for (int st = 1; st <= 8; st <<= 1) {
        mm += __shfl_xor(mm, st);
        #pragma unroll
        for (int r = 0; r < 5; ++r) d[r] += __shfl_xor(d[r], st);
    }
    if (l16 == 0) {
        float mn = sqrtf(mm);
        float e[5];
        #pragma unroll
        for (int r = 0; r < 4; ++r) {
            float c = d[r] / fmaxf(knorm[r] * mn, EPSC);
            e[r] = expf(c);
            ws[WS_ER + (b * R + r) * N + n] = e[r];
        }
        float cw = d[4] / fmaxf(knorm[4] * mn, EPSC);
        e[4] = expf(cw * wstr[b]);
        ws[WS_EW + b * N + n] = e[4];
        #pragma unroll
        for (int q = 0; q < 5; ++q) epart[q][rloc] = e[q];
    }
    __syncthreads();
    if (t < 80) {
        int q = t >> 4, i = t & 15;
        float v = epart[q][i];
        #pragma unroll
        for (int st = 1; st <= 8; st <<= 1) v += __shfl_xor(v, st);
        if (i == 0) atomicAdd(&ws[WS_KSUM + b * 5 + q], v);
    }
}

// ===================== K2: allocation cumprod + ww (lightweight) =====================
// grid B, block 1024 (one element per thread).
__global__ void k2_soft(const float* __restrict__ usage,
                        const float* __restrict__ agate,
                        const float* __restrict__ wgate,
                        float* __restrict__ ws) {
    int b = blockIdx.x, t = threadIdx.x;
    int lane = t & 63, wv = t >> 6;       // 16 waves
    __shared__ float wsc[16];
    __shared__ float red[16];

    float sw = ws[WS_KSUM + b * 5 + 4];
    float wcv = ws[WS_EW + b * N + t] / sw;

    // ---- exclusive cumprod scan of usage ----
    float u = usage[b * N + t];
    float incl = u;
    #pragma unroll
    for (int s = 1; s <= 32; s <<= 1) {
        float up = __shfl_up(incl, s);
        if (lane >= s) incl *= up;
    }
    if (lane == 63) wsc[wv] = incl;
    __syncthreads();
    if (t < 16) {
        float v = wsc[t];
        #pragma unroll
        for (int s = 1; s <= 8; s <<= 1) {
            float up = __shfl_up(v, s);
            if (lane >= s) v *= up;
        }
        wsc[t] = v;  // inclusive over waves
    }
    __syncthreads();
    float woff = (wv == 0) ? 1.f : wsc[wv - 1];
    float eu = __shfl_up(incl, 1);
    float excl = (lane == 0 ? 1.f : eu) * woff;
    float alloc = (1.f - u) * excl;

    float wwv = (agate[b] * (alloc - wcv) + wcv) * wgate[b];
    ws[WS_WW + b * N + t] = wwv;

    float s6 = wwv;
    #pragma unroll
    for (int s = 1; s <= 32; s <<= 1) s6 += __shfl_xor(s6, s);
    __syncthreads();
    if (lane == 0) red[wv] = s6;
    __syncthreads();
    if (t == 0) {
        float acc = 0.f;
        for (int w2 = 0; w2 < 16; ++w2) acc += red[w2];
        atomicAdd(&ws[WS_SUM], acc);
    }
}

// ===================== K3: single pass over L (R3 geometry) =====================
// grid B*16 (64-row strips), block 256. Thread owns 4 fixed cols.
// 8-row batched loads (MLP=8), bw register-accumulated, fw via LDS
// transpose-reduce, NT stores for link_new.
__global__ void k3_link(const float* __restrict__ L,
                        const float* __restrict__ rw,
                        const float* __restrict__ prec,
                        float* __restrict__ ws,
                        float* __restrict__ out) {
    int bx = blockIdx.x;
    int b = bx >> 4;
    int strip = bx & 15;
    int i0 = strip << 6;
    int t = threadIdx.x;
    __shared__ float scratch[256][36];   // padded: float4-aligned, low-conflict
    __shared__ float ww_row[64];
    __shared__ float rw_row[R][64];

    if (t < 64) ww_row[t] = ws[WS_WW + b * N + i0 + t];
    for (int idx = t; idx < R * 64; idx += 256) {
        int r = idx >> 6, i = idx & 63;
        rw_row[r][i] = rw[(b * R + r) * N + i0 + i];
    }
    __syncthreads();

    int j0 = 4 * t;
    float4 wwj = *reinterpret_cast<const float4*>(ws + WS_WW + b * N + j0);
    float4 pj  = *reinterpret_cast<const float4*>(prec + b * N + j0);
    float4 rwj[R];
    #pragma unroll
    for (int r = 0; r < R; ++r)
        rwj[r] = *reinterpret_cast<const float4*>(rw + (b * R + r) * N + j0);
    float4 bwa[R];
    #pragma unroll
    for (int r = 0; r < R; ++r) bwa[r] = make_float4(0.f, 0.f, 0.f, 0.f);

    const float* Lr = L + ((size_t)(b * N + i0)) * N + j0;
    float* Or = out + O_LINK + ((size_t)(b * N + i0)) * N + j0;

    int g = t >> 3, kk = t & 7;   // reduce-phase role: output g, reducer kk

    for (int batch = 0; batch < 8; ++batch) {
        // --- issue 8 independent loads ---
        float4 v[8];
        #pragma unroll
        for (int k = 0; k < 8; ++k)
            v[k] = *reinterpret_cast<const float4*>(Lr + (size_t)(batch * 8 + k) * N);

        float4 fwp[8];
        #pragma unroll
        for (int k = 0; k < 8; ++k) {
            int row = batch * 8 + k;
            float wi = ww_row[row];
            float c = 1.f - wi;
            f32x4 o;
            o.x = (c - wwj.x) * v[k].x + wi * pj.x;
            o.y = (c - wwj.y) * v[k].y + wi * pj.y;
            o.z = (c - wwj.z) * v[k].z + wi * pj.z;
            o.w = (c - wwj.w) * v[k].w + wi * pj.w;
            __builtin_nontemporal_store(o,
                reinterpret_cast<f32x4*>(Or + (size_t)row * N));
            float4 f;
            f.x = v[k].x*rwj[0].x + v[k].y*rwj[0].y + v[k].z*rwj[0].z + v[k].w*rwj[0].w;
            f.y = v[k].x*rwj[1].x + v[k].y*rwj[1].y + v[k].z*rwj[1].z + v[k].w*rwj[1].w;
            f.z = v[k].x*rwj[2].x + v[k].y*rwj[2].y + v[k].z*rwj[2].z + v[k].w*rwj[2].w;
            f.w = v[k].x*rwj[3].x + v[k].y*rwj[3].y + v[k].z*rwj[3].z + v[k].w*rwj[3].w;
            fwp[k] = f;
            #pragma unroll
            for (int r = 0; r < R; ++r) {
                float q = rw_row[r][row];
                bwa[r].x += q * v[k].x; bwa[r].y += q * v[k].y;
                bwa[r].z += q * v[k].z; bwa[r].w += q * v[k].w;
            }
        }

        // --- fw transpose-reduce: scratch[t][row_k*4 + r] = partial ---
        #pragma unroll
        for (int k = 0; k < 8; ++k)
            *reinterpret_cast<float4*>(&scratch[t][k * 4]) = fwp[k];
        __syncthreads();
        float s = 0.f;
        #pragma unroll
        for (int m = 0; m < 32; ++m) s += scratch[kk + 8 * m][g];
        s += __shfl_xor(s, 1);
        s += __shfl_xor(s, 2);
        s += __shfl_xor(s, 4);
        if (kk == 0) {
            int rowk = g >> 2, r = g & 3;
            ws[WS_FW + (b * R + r) * N + i0 + batch * 8 + rowk] = s;
        }
        __syncthreads();
    }

    // bw: per-strip partials to ws (no global atomics)
    float* bwout = ws + WS_BW + (size_t)(b * 16 + strip) * R * N;
    #pragma unroll
    for (int r = 0; r < R; ++r)
        *reinterpret_cast<float4*>(bwout + r * N + j0) = bwa[r];
}

// ===================== K4: finalize =====================
// grid B*16 (64-row chunks), block 256.
__global__ void k4_final(const float* __restrict__ mem,
                         const float* __restrict__ usage,
                         const float* __restrict__ prec,
                         const float* __restrict__ rmodes,
                         const float* __restrict__ rstr,
                         const float* __restrict__ fgates,
                         const float* __restrict__ ev,
                         const float* __restrict__ wvec,
                         float* __restrict__ ws,
                         float* __restrict__ out) {
    int bx = blockIdx.x;
    int b = bx >> 4;
    int n0 = (bx & 15) << 6;
    int t = threadIdx.x;
    __shared__ float nrw[R][64];
    __shared__ float wwl[64];
    __shared__ float rrl[2][R][W];

    // phase 1: new_rw (256 = R*64 work items); content weight finished inline
    {
        int r = t >> 6, nl = t & 63, n = n0 + nl;
        float bs = 0.f;
        #pragma unroll
        for (int tile = 0; tile < 16; ++tile)
            bs += ws[WS_BW + ((size_t)(b * 16 + tile) * R + r) * N + n];
        float fwv = ws[WS_FW + (b * R + r) * N + n];
        float cv  = ws[WS_ER + (b * R + r) * N + n] / ws[WS_KSUM + b * 5 + r]
                    * rstr[b * R + r];
        float m0 = rmodes[(b * R + r) * 3 + 0];
        float m1 = rmodes[(b * R + r) * 3 + 1];
        float m2 = rmodes[(b * R + r) * 3 + 2];
        float v = fwv * m0 + bs * m1 + cv * m2;
        out[O_NRW + (b * R + r) * N + n] = v;
        nrw[r][nl] = v;
    }
    __syncthreads();

    // phase 2: usage_new, precedence_new
    if (t < 64) {
        int n = n0 + t;
        float ret = 1.f;
        #pragma unroll
        for (int r = 0; r < R; ++r) ret *= (1.f - fgates[b * R + r] * nrw[r][t]);
        float u = usage[b * N + n];
        float w = ws[WS_WW + b * N + n];
        out[O_USAGE + b * N + n] = (u + w - u * w) * ret;
        float S = ws[WS_SUM];
        out[O_PREC + b * N + n] = (1.f - S) * prec[b * N + n] + w;
        wwl[t] = w;
    }
    __syncthreads();

    // phase 3: memory_new + read_result partial
    int wi = t & 127, half = t >> 7;
    float er = ev[b * W + wi], wvv = wvec[b * W + wi];
    float acc[R] = {0.f, 0.f, 0.f, 0.f};
    for (int k = 0; k < 32; ++k) {
        int nl = half * 32 + k;
        int n = n0 + nl;
        size_t off = ((size_t)(b * N + n)) * W + wi;
        float m = mem[off];
        float wn = wwl[nl];
        out[O_MEM + off] = m * (1.f - wn * er) + wn * wvv;
        #pragma unroll
        for (int r = 0; r < R; ++r) acc[r] += nrw[r][nl] * m;
    }
    #pragma unroll
    for (int r = 0; r < R; ++r) rrl[half][r][wi] = acc[r];
    __syncthreads();
    for (int idx = t; idx < R * W; idx += 256) {
        int r = idx >> 7, w2 = idx & 127;
        atomicAdd(&out[O_RR + (b * R + r) * W + w2], rrl[0][r][w2] + rrl[1][r][w2]);
    }
}

extern "C" void kernel_launch(void* const* d_in, const int* in_sizes, int n_in,
                              void* d_out, int out_size, void* d_ws, size_t ws_size,
                              hipStream_t stream) {
    const float* mem    = (const float*)d_in[0];
    const float* L      = (const float*)d_in[1];
    const float* usage  = (const float*)d_in[2];
    const float* prec   = (const float*)d_in[3];
    const float* rw     = (const float*)d_in[4];
    const float* rkeys  = (const float*)d_in[5];
    const float* rstr   = (const float*)d_in[6];
    const float* rmodes = (const float*)d_in[7];
    const float* wkey   = (const float*)d_in[8];
    const float* wstr   = (const float*)d_in[9];
    const float* ag     = (const float*)d_in[10];
    const float* wg     = (const float*)d_in[11];
    const float* wv     = (const float*)d_in[12];
    const float* ev     = (const float*)d_in[13];
    const float* fg     = (const float*)d_in[14];
    float* out = (float*)d_out;
    float* ws  = (float*)d_ws;

    (void)hipMemsetAsync(ws, 0, 1024, stream);                               // sum_ww + ksum
    (void)hipMemsetAsync(out, 0, (size_t)B * R * W * sizeof(float), stream); // read_result

    k1_scores<<<B * 64, 256, 0, stream>>>(mem, rkeys, wkey, wstr, ws);
    k2_soft<<<B, 1024, 0, stream>>>(usage, ag, wg, ws);
    k3_link<<<B * 16, 256, 0, stream>>>(L, rw, prec, ws, out);
    k4_final<<<B * 16, 256, 0, stream>>>(mem, usage, prec, rmodes, rstr, fg, ev, wv, ws, out);
}

// Round 7
// 84.096 us; speedup vs baseline: 1.0598x; 1.0057x over previous
//
#include <hip/hip_runtime.h>
#include <math.h>

#define B 32
#define N 1024
#define W 128
#define R 4
#define EPSC 1e-8f

typedef float f32x4 __attribute__((ext_vector_type(4)));

// ---- ws layout (in floats) ----
#define WS_SUM   0                              // 1 float
#define WS_KSUM  64                             // B*5 softmax denominators
#define WS_BW    256                            // B*16*R*N
#define WS_FW    (WS_BW + B*16*R*N)             // B*R*N
#define WS_ER    (WS_FW + B*R*N)                // B*R*N  exp(cos) read keys
#define WS_EW    (WS_ER + B*R*N)                // B*N    exp(cos*wstr) write key
#define WS_WW    (WS_EW + B*N)                  // B*N

// ---- out offsets (in floats) ----
#define O_RR    0
#define O_MEM   (O_RR + B*R*W)
#define O_LINK  (O_MEM + B*N*W)
#define O_USAGE (O_LINK + B*N*N)
#define O_PREC  (O_USAGE + B*N)
#define O_NRW   (O_PREC + B*N)

// ===================== K1: cosine scores + exp + partial sums =====================
// grid B*64 (16 rows/block), block 256. 16 lanes per row -> 4-level reduce.
// No-max softmax: cos in [-1,1], write score in [-2,2] -> exp safe directly.
__global__ void k1_scores(const float* __restrict__ mem,
                          const float* __restrict__ rkeys,
                          const float* __restrict__ wkey,
                          const float* __restrict__ wstr,
                          float* __restrict__ ws) {
    int bx = blockIdx.x;
    int b = bx >> 6;
    int n0 = (bx & 63) << 4;
    int t = threadIdx.x;
    __shared__ float keys[5][W];
    __shared__ float knorm[5];
    __shared__ float epart[5][16];
    for (int idx = t; idx < 5 * W; idx += 256) {
        int r = idx >> 7, w = idx & 127;
        keys[r][w] = (r < 4) ? rkeys[(b * R + r) * W + w] : wkey[b * W + w];
    }
    __syncthreads();
    if (t < 160) {
        int kidx = t >> 5, l = t & 31;
        float s = 0.f;
        #pragma unroll
        for (int c = 0; c < 4; ++c) { float v = keys[kidx][l * 4 + c]; s += v * v; }
        #pragma unroll
        for (int st = 1; st <= 16; st <<= 1) s += __shfl_xor(s, st);
        if (l == 0) knorm[kidx] = sqrtf(s);
    }
    __syncthreads();
    int l16 = t & 15;
    int rloc = t >> 4;          // 0..15
    int n = n0 + rloc;
    const float* mrow = mem + ((size_t)(b * N + n)) * W + l16 * 8;
    float4 a  = *reinterpret_cast<const float4*>(mrow);
    float4 a2 = *reinterpret_cast<const float4*>(mrow + 4);
    float mm = a.x*a.x + a.y*a.y + a.z*a.z + a.w*a.w
             + a2.x*a2.x + a2.y*a2.y + a2.z*a2.z + a2.w*a2.w;
    float d[5];
    #pragma unroll
    for (int r = 0; r < 5; ++r) {
        float4 k1v = *reinterpret_cast<const float4*>(&keys[r][l16 * 8]);
        float4 k2v = *reinterpret_cast<const float4*>(&keys[r][l16 * 8 + 4]);
        d[r] = a.x*k1v.x + a.y*k1v.y + a.z*k1v.z + a.w*k1v.w
             + a2.x*k2v.x + a2.y*k2v.y + a2.z*k2v.z + a2.w*k2v.w;
    }
    #pragma unroll
    for (int st = 1; st <= 8; st <<= 1) {
        mm += __shfl_xor(mm, st);
        #pragma unroll
        for (int r = 0; r < 5; ++r) d[r] += __shfl_xor(d[r], st);
    }
    if (l16 == 0) {
        float mn = sqrtf(mm);
        float e[5];
        #pragma unroll
        for (int r = 0; r < 4; ++r) {
            float c = d[r] / fmaxf(knorm[r] * mn, EPSC);
            e[r] = expf(c);
            ws[WS_ER + (b * R + r) * N + n] = e[r];
        }
        float cw = d[4] / fmaxf(knorm[4] * mn, EPSC);
        e[4] = expf(cw * wstr[b]);
        ws[WS_EW + b * N + n] = e[4];
        #pragma unroll
        for (int q = 0; q < 5; ++q) epart[q][rloc] = e[q];
    }
    __syncthreads();
    if (t < 80) {
        int q = t >> 4, i = t & 15;
        float v = epart[q][i];
        #pragma unroll
        for (int st = 1; st <= 8; st <<= 1) v += __shfl_xor(v, st);
        if (i == 0) atomicAdd(&ws[WS_KSUM + b * 5 + q], v);
    }
}

// ===================== K3: ww scan + single pass over L =====================
// grid B*16 (64-row strips), block 256. Prologue recomputes the usage
// cumprod scan + ww per block (replaces k2; strip 0 publishes WS_WW/WS_SUM).
// Main loop: thread owns 4 fixed cols; 8-row batched loads (MLP=8), bw
// register-accumulated, fw via LDS transpose-reduce, NT stores for link_new.
__global__ void k3_link(const float* __restrict__ L,
                        const float* __restrict__ rw,
                        const float* __restrict__ prec,
                        const float* __restrict__ usage,
                        const float* __restrict__ agate,
                        const float* __restrict__ wgate,
                        float* __restrict__ ws,
                        float* __restrict__ out) {
    int bx = blockIdx.x;
    int b = bx >> 4;
    int strip = bx & 15;
    int i0 = strip << 6;
    int t = threadIdx.x;
    int lane = t & 63, wv = t >> 6;
    __shared__ float scratch[256][36];   // padded: float4-aligned, low-conflict
    __shared__ float ww_l[N];
    __shared__ float rw_row[R][64];
    __shared__ float wpart[4];
    __shared__ float red[4];

    int j0 = 4 * t;

    // ---- inline ww computation (was k2) ----
    float4 u4 = *reinterpret_cast<const float4*>(usage + b * N + j0);
    float4 e4 = *reinterpret_cast<const float4*>(ws + WS_EW + b * N + j0);
    float ksw = ws[WS_KSUM + b * 5 + 4];
    float p = u4.x * u4.y * u4.z * u4.w;
    float incl = p;
    #pragma unroll
    for (int s = 1; s <= 32; s <<= 1) {
        float up = __shfl_up(incl, s);
        if (lane >= s) incl *= up;
    }
    if (lane == 63) wpart[wv] = incl;
    // independent: stage rw rows for this strip
    for (int idx = t; idx < R * 64; idx += 256) {
        int r = idx >> 6, i = idx & 63;
        rw_row[r][i] = rw[(b * R + r) * N + i0 + i];
    }
    __syncthreads();
    float woff = 1.f;
    #pragma unroll
    for (int w = 0; w < 3; ++w) if (w < wv) woff *= wpart[w];
    float eu = __shfl_up(incl, 1);
    float excl = (lane == 0 ? 1.f : eu) * woff;
    float ag = agate[b], wg = wgate[b];
    float invk = 1.f / ksw;
    float e0 = excl, e1 = e0 * u4.x, e2 = e1 * u4.y, e3 = e2 * u4.z;
    float wc0 = e4.x * invk, wc1 = e4.y * invk, wc2 = e4.z * invk, wc3 = e4.w * invk;
    float4 wwj;
    wwj.x = (ag * ((1.f - u4.x) * e0 - wc0) + wc0) * wg;
    wwj.y = (ag * ((1.f - u4.y) * e1 - wc1) + wc1) * wg;
    wwj.z = (ag * ((1.f - u4.z) * e2 - wc2) + wc2) * wg;
    wwj.w = (ag * ((1.f - u4.w) * e3 - wc3) + wc3) * wg;
    *reinterpret_cast<float4*>(&ww_l[j0]) = wwj;
    float lsum = wwj.x + wwj.y + wwj.z + wwj.w;
    #pragma unroll
    for (int s = 1; s <= 32; s <<= 1) lsum += __shfl_xor(lsum, s);
    if (lane == 0) red[wv] = lsum;
    if (strip == 0)
        *reinterpret_cast<float4*>(ws + WS_WW + b * N + j0) = wwj;  // publish for k4
    __syncthreads();
    if (t == 0 && strip == 0)
        atomicAdd(&ws[WS_SUM], red[0] + red[1] + red[2] + red[3]);

    // ---- main pass over L ----
    float4 pj  = *reinterpret_cast<const float4*>(prec + b * N + j0);
    float4 rwj[R];
    #pragma unroll
    for (int r = 0; r < R; ++r)
        rwj[r] = *reinterpret_cast<const float4*>(rw + (b * R + r) * N + j0);
    float4 bwa[R];
    #pragma unroll
    for (int r = 0; r < R; ++r) bwa[r] = make_float4(0.f, 0.f, 0.f, 0.f);

    const float* Lr = L + ((size_t)(b * N + i0)) * N + j0;
    float* Or = out + O_LINK + ((size_t)(b * N + i0)) * N + j0;

    int g = t >> 3, kk = t & 7;   // reduce-phase role: output g, reducer kk

    for (int batch = 0; batch < 8; ++batch) {
        // --- issue 8 independent loads ---
        float4 v[8];
        #pragma unroll
        for (int k = 0; k < 8; ++k)
            v[k] = *reinterpret_cast<const float4*>(Lr + (size_t)(batch * 8 + k) * N);

        float4 fwp[8];
        #pragma unroll
        for (int k = 0; k < 8; ++k) {
            int row = batch * 8 + k;
            float wi = ww_l[i0 + row];
            float c = 1.f - wi;
            f32x4 o;
            o.x = (c - wwj.x) * v[k].x + wi * pj.x;
            o.y = (c - wwj.y) * v[k].y + wi * pj.y;
            o.z = (c - wwj.z) * v[k].z + wi * pj.z;
            o.w = (c - wwj.w) * v[k].w + wi * pj.w;
            __builtin_nontemporal_store(o,
                reinterpret_cast<f32x4*>(Or + (size_t)row * N));
            float4 f;
            f.x = v[k].x*rwj[0].x + v[k].y*rwj[0].y + v[k].z*rwj[0].z + v[k].w*rwj[0].w;
            f.y = v[k].x*rwj[1].x + v[k].y*rwj[1].y + v[k].z*rwj[1].z + v[k].w*rwj[1].w;
            f.z = v[k].x*rwj[2].x + v[k].y*rwj[2].y + v[k].z*rwj[2].z + v[k].w*rwj[2].w;
            f.w = v[k].x*rwj[3].x + v[k].y*rwj[3].y + v[k].z*rwj[3].z + v[k].w*rwj[3].w;
            fwp[k] = f;
            #pragma unroll
            for (int r = 0; r < R; ++r) {
                float q = rw_row[r][row];
                bwa[r].x += q * v[k].x; bwa[r].y += q * v[k].y;
                bwa[r].z += q * v[k].z; bwa[r].w += q * v[k].w;
            }
        }

        // --- fw transpose-reduce: scratch[t][row_k*4 + r] = partial ---
        #pragma unroll
        for (int k = 0; k < 8; ++k)
            *reinterpret_cast<float4*>(&scratch[t][k * 4]) = fwp[k];
        __syncthreads();
        float s = 0.f;
        #pragma unroll
        for (int m = 0; m < 32; ++m) s += scratch[kk + 8 * m][g];
        s += __shfl_xor(s, 1);
        s += __shfl_xor(s, 2);
        s += __shfl_xor(s, 4);
        if (kk == 0) {
            int rowk = g >> 2, r = g & 3;
            ws[WS_FW + (b * R + r) * N + i0 + batch * 8 + rowk] = s;
        }
        __syncthreads();
    }

    // bw: per-strip partials to ws (no global atomics)
    float* bwout = ws + WS_BW + (size_t)(b * 16 + strip) * R * N;
    #pragma unroll
    for (int r = 0; r < R; ++r)
        *reinterpret_cast<float4*>(bwout + r * N + j0) = bwa[r];
}

// ===================== K4: finalize =====================
// grid B*16 (64-row chunks), block 256.
__global__ void k4_final(const float* __restrict__ mem,
                         const float* __restrict__ usage,
                         const float* __restrict__ prec,
                         const float* __restrict__ rmodes,
                         const float* __restrict__ rstr,
                         const float* __restrict__ fgates,
                         const float* __restrict__ ev,
                         const float* __restrict__ wvec,
                         float* __restrict__ ws,
                         float* __restrict__ out) {
    int bx = blockIdx.x;
    int b = bx >> 4;
    int n0 = (bx & 15) << 6;
    int t = threadIdx.x;
    __shared__ float nrw[R][64];
    __shared__ float wwl[64];
    __shared__ float rrl[2][R][W];

    // phase 1: new_rw (256 = R*64 work items); content weight finished inline
    {
        int r = t >> 6, nl = t & 63, n = n0 + nl;
        float bs = 0.f;
        #pragma unroll
        for (int tile = 0; tile < 16; ++tile)
            bs += ws[WS_BW + ((size_t)(b * 16 + tile) * R + r) * N + n];
        float fwv = ws[WS_FW + (b * R + r) * N + n];
        float cv  = ws[WS_ER + (b * R + r) * N + n] / ws[WS_KSUM + b * 5 + r]
                    * rstr[b * R + r];
        float m0 = rmodes[(b * R + r) * 3 + 0];
        float m1 = rmodes[(b * R + r) * 3 + 1];
        float m2 = rmodes[(b * R + r) * 3 + 2];
        float v = fwv * m0 + bs * m1 + cv * m2;
        out[O_NRW + (b * R + r) * N + n] = v;
        nrw[r][nl] = v;
    }
    __syncthreads();

    // phase 2: usage_new, precedence_new
    if (t < 64) {
        int n = n0 + t;
        float ret = 1.f;
        #pragma unroll
        for (int r = 0; r < R; ++r) ret *= (1.f - fgates[b * R + r] * nrw[r][t]);
        float u = usage[b * N + n];
        float w = ws[WS_WW + b * N + n];
        out[O_USAGE + b * N + n] = (u + w - u * w) * ret;
        float S = ws[WS_SUM];
        out[O_PREC + b * N + n] = (1.f - S) * prec[b * N + n] + w;
        wwl[t] = w;
    }
    __syncthreads();

    // phase 3: memory_new + read_result partial
    int wi = t & 127, half = t >> 7;
    float er = ev[b * W + wi], wvv = wvec[b * W + wi];
    float acc[R] = {0.f, 0.f, 0.f, 0.f};
    for (int k = 0; k < 32; ++k) {
        int nl = half * 32 + k;
        int n = n0 + nl;
        size_t off = ((size_t)(b * N + n)) * W + wi;
        float m = mem[off];
        float wn = wwl[nl];
        out[O_MEM + off] = m * (1.f - wn * er) + wn * wvv;
        #pragma unroll
        for (int r = 0; r < R; ++r) acc[r] += nrw[r][nl] * m;
    }
    #pragma unroll
    for (int r = 0; r < R; ++r) rrl[half][r][wi] = acc[r];
    __syncthreads();
    for (int idx = t; idx < R * W; idx += 256) {
        int r = idx >> 7, w2 = idx & 127;
        atomicAdd(&out[O_RR + (b * R + r) * W + w2], rrl[0][r][w2] + rrl[1][r][w2]);
    }
}

extern "C" void kernel_launch(void* const* d_in, const int* in_sizes, int n_in,
                              void* d_out, int out_size, void* d_ws, size_t ws_size,
                              hipStream_t stream) {
    const float* mem    = (const float*)d_in[0];
    const float* L      = (const float*)d_in[1];
    const float* usage  = (const float*)d_in[2];
    const float* prec   = (const float*)d_in[3];
    const float* rw     = (const float*)d_in[4];
    const float* rkeys  = (const float*)d_in[5];
    const float* rstr   = (const float*)d_in[6];
    const float* rmodes = (const float*)d_in[7];
    const float* wkey   = (const float*)d_in[8];
    const float* wstr   = (const float*)d_in[9];
    const float* ag     = (const float*)d_in[10];
    const float* wg     = (const float*)d_in[11];
    const float* wv     = (const float*)d_in[12];
    const float* ev     = (const float*)d_in[13];
    const float* fg     = (const float*)d_in[14];
    float* out = (float*)d_out;
    float* ws  = (float*)d_ws;

    (void)hipMemsetAsync(ws, 0, 1024, stream);                               // sum_ww + ksum
    (void)hipMemsetAsync(out, 0, (size_t)B * R * W * sizeof(float), stream); // read_result

    k1_scores<<<B * 64, 256, 0, stream>>>(mem, rkeys, wkey, wstr, ws);
    k3_link<<<B * 16, 256, 0, stream>>>(L, rw, prec, usage, ag, wg, ws, out);
    k4_final<<<B * 16, 256, 0, stream>>>(mem, usage, prec, rmodes, rstr, fg, ev, wv, ws, out);
}